// Round 15
// baseline (153.971 us; speedup 1.0000x reference)
//
#include <hip/hip_runtime.h>
#include <math.h>

#define EPSV 1e-5f

// conv1 (3-tap, zero-pad) + relu at the 3 positions of one sample
__device__ __forceinline__ void conv3_relu(float x0, float x1, float x2,
                                           float wa, float wb, float wc, float bb,
                                           float& t0, float& t1, float& t2)
{
    t0 = fmaxf(fmaf(wb, x0, fmaf(wc, x1, bb)), 0.f);
    t1 = fmaxf(fmaf(wa, x0, fmaf(wb, x1, fmaf(wc, x2, bb))), 0.f);
    t2 = fmaxf(fmaf(wa, x1, fmaf(wb, x2, bb)), 0.f);
}

// ---------------------------------------------------------------------------
// R24 = R23 (142.3us best) + memset-node elimination (last structural lever):
//  - k_stats1 tail: plain per-block stores p1[block*32+t] (full overwrite,
//    no zeroing, no atomics). Blocks 0..7 also zero accB (1 predicated
//    store/thread; k_stats1->k_stats2 boundary orders it before atomics).
//  - k_stats2 prologue: R12-PROVEN p1-reduce loop (ran inside stats2 from
//    R12-R17 harmlessly; the poisons were fin2-epilogue-in-stats2 [R18] and
//    loops-in-k_final [R17], both absent).
//  - k_final byte-identical to R23 ((256,2), NSHARD_B=32 fixed prologue).
//  - launcher: hipMemsetAsync dropped -> 3 nodes.
// Pre-commit: total >= 141 -> revert to R23, declare structural floor.
// Accounting at R23: fill ~44 (harness) + final ~35 + stats ~10 + memset ~1
// + ~50 of node gaps (~10/node).
// ---------------------------------------------------------------------------

#define NSHARD_B 32   // stats2: nb2=2048 blocks -> 64 adds/addr

// ---------------------------------------------------------------------------
// Pass 1: per-channel sum/sumsq of relu(conv1(x)+b1), 16 ch.
// Group-outer / sample-inner. Prologue: blocks 0..7 zero accB (2048 floats).
// Tail: block-reduce in LDS then plain stores p1[block*32 + v]
// (v<16 sum, v>=16 sq).
// ---------------------------------------------------------------------------
__global__ __launch_bounds__(256) void k_stats1(const float* __restrict__ x,
                                                const float* __restrict__ w1,
                                                const float* __restrict__ b1,
                                                float* __restrict__ p1,
                                                float* __restrict__ accB,
                                                int B)
{
    __shared__ float4 sW1[16];
    int t = threadIdx.x;
    // zero accB for k_stats2's sharded atomics (ws is poison-filled each
    // iteration; kernel boundary orders this before any accB atomicAdd)
    if (blockIdx.x < 8) accB[blockIdx.x * 256 + t] = 0.f;
    if (t < 16) sW1[t] = make_float4(w1[3*t], w1[3*t+1], w1[3*t+2], b1[t]);
    __syncthreads();

    float cur[32];   // [0,16): sum, [16,32): sq
#pragma unroll
    for (int i = 0; i < 32; ++i) cur[i] = 0.f;

    auto upd = [&](int g, float t0, float t1, float t2) {
        cur[g]      += t0 + t1 + t2;
        cur[16 + g]  = fmaf(t0, t0, fmaf(t1, t1, fmaf(t2, t2, cur[16 + g])));
    };

    auto accum1 = [&](float x0, float x1, float x2) {   // tail only
#pragma unroll
        for (int g = 0; g < 16; ++g) {
            float4 w = sW1[g];
            float t0, t1, t2;
            conv3_relu(x0, x1, x2, w.x, w.y, w.z, w.w, t0, t1, t2);
            upd(g, t0, t1, t2);
        }
    };

    int nchunk = (B + 3) >> 2;
    for (int ch = blockIdx.x * 256 + t; ch < nchunk; ch += gridDim.x * 256) {
        int s0 = ch << 2;
        if (s0 + 4 <= B) {
            const float4* xp = (const float4*)(x + (size_t)s0 * 3);
            float4 A = xp[0], Bq = xp[1], Cq = xp[2];
            const float xs[4][3] = {{A.x,  A.y,  A.z },
                                    {A.w,  Bq.x, Bq.y},
                                    {Bq.z, Bq.w, Cq.x},
                                    {Cq.y, Cq.z, Cq.w}};
#pragma unroll
            for (int g = 0; g < 16; ++g) {
                float4 w = sW1[g];           // 1 LDS read per 4 samples
#pragma unroll
                for (int m = 0; m < 4; ++m) {
                    float t0, t1, t2;
                    conv3_relu(xs[m][0], xs[m][1], xs[m][2],
                               w.x, w.y, w.z, w.w, t0, t1, t2);
                    upd(g, t0, t1, t2);
                }
            }
        } else {
            for (int m = 0; m < 4; ++m) {
                int s = s0 + m;
                if (s < B) accum1(x[3*s], x[3*s+1], x[3*s+2]);
            }
        }
    }

    // xor-tree: lane (L&31) ends holding total of slot (L&31)  [R3-proven]
    int lane = t & 63, wid = t >> 6;
#pragma unroll
    for (int i = 0; i < 32; ++i) cur[i] += __shfl_xor(cur[i], 32, 64);
#pragma unroll
    for (int half = 16; half >= 1; half >>= 1) {
#pragma unroll
        for (int i = 0; i < half; ++i) {
            bool up = (lane & half);
            float keep = up ? cur[i + half] : cur[i];
            float send = up ? cur[i] : cur[i + half];
            cur[i] = keep + __shfl_xor(send, half, 64);
        }
    }
    __shared__ float red[4][32];
    if (lane < 32) red[wid][lane] = cur[0];
    __syncthreads();
    if (t < 32)
        p1[blockIdx.x * 32 + t] = red[0][t] + red[1][t] + red[2][t] + red[3][t];
}

// ---------------------------------------------------------------------------
// Pass 2: conv2 per-channel stats, lane-pair split (parity p=tid&1 owns conv
// groups [8p,8p+8)). Prologue: R12-proven p1-reduce -> BN1 -> sU/sC.
// Block 0 publishes sU/sC to global wU/wC for k_final. Tail: 64 sharded
// atomicAdds into 32 shards (accB pre-zeroed by k_stats1). NO epilogue.
// accB[shard*64 + v]: v<32 sum ch v, v>=32 sq ch v-32.
// ---------------------------------------------------------------------------
__global__ __launch_bounds__(256) void k_stats2(const float* __restrict__ x,
                                                const float* __restrict__ w1,
                                                const float* __restrict__ b1,
                                                const float* __restrict__ p1,
                                                const float* __restrict__ g1,
                                                const float* __restrict__ bt1,
                                                const float* __restrict__ w2,
                                                const float* __restrict__ b2,
                                                float* __restrict__ accB,
                                                float4* __restrict__ wU,
                                                float2* __restrict__ wC,
                                                float Ninv, int nb1, int B)
{
    __shared__ float4 sW1[16];
    __shared__ float4 sU[32];   // ua,ub,uc,c0
    __shared__ float2 sC[32];   // c1,c2
    __shared__ float4 redbuf[256];
    __shared__ float tot[32];
    __shared__ float ssc[16], ssh[16];
    int t = threadIdx.x;

    // ---- R12-proven fin1 prologue: reduce p1 -> BN1 scale/shift
    {
        int v4 = t & 7, c = t >> 3;          // 8 float4 per p1 row
        float4 a = make_float4(0.f, 0.f, 0.f, 0.f);
        for (int b = c; b < nb1; b += 32) {
            float4 p = ((const float4*)p1)[b * 8 + v4];
            a.x += p.x; a.y += p.y; a.z += p.z; a.w += p.w;
        }
        redbuf[c * 8 + v4] = a;
    }
    if (t < 16) sW1[t] = make_float4(w1[3*t], w1[3*t+1], w1[3*t+2], b1[t]);
    __syncthreads();
    if (t < 8) {
        float4 a = make_float4(0.f, 0.f, 0.f, 0.f);
#pragma unroll
        for (int c = 0; c < 32; ++c) {
            float4 p = redbuf[c * 8 + t];
            a.x += p.x; a.y += p.y; a.z += p.z; a.w += p.w;
        }
        tot[4*t+0] = a.x; tot[4*t+1] = a.y; tot[4*t+2] = a.z; tot[4*t+3] = a.w;
    }
    __syncthreads();
    if (t < 16) {
        float mean = tot[t] * Ninv;
        float var  = fmaxf(tot[16 + t] * Ninv - mean * mean, 0.f);
        float rstd = rsqrtf(var + EPSV);
        float sc = g1[t] * rstd;
        ssc[t] = sc;
        ssh[t] = bt1[t] - mean * sc;
    }
    __syncthreads();
    if (t < 32) {
        int o = t, g = o >> 1;
        float sc = ssc[g], sh = ssh[g];
        float wv0 = w2[3*o], wv1 = w2[3*o+1], wv2 = w2[3*o+2];
        sU[o] = make_float4(wv0 * sc, wv1 * sc, wv2 * sc,
                            b2[o] + sh * (wv1 + wv2));          // bias pos0
        sC[o] = make_float2(b2[o] + sh * (wv0 + wv1 + wv2),     // bias pos1
                            b2[o] + sh * (wv0 + wv1));          // bias pos2
    }
    __syncthreads();
    // block 0 publishes folded conv2 tables for k_final (kernel boundary
    // orders these stores vs k_final's loads)
    if (blockIdx.x == 0 && t < 32) { wU[t] = sU[t]; wC[t] = sC[t]; }

    const int p = t & 1;        // parity: which half of the channels
    const int gbase = 8 * p;    // conv groups [gbase, gbase+8)

    float cur[32];  // [0,16): sum ch 16p+i, [16,32): sq ch 16p+i
#pragma unroll
    for (int i = 0; i < 32; ++i) cur[i] = 0.f;

    auto updc = [&](int oc, float v0, float v1, float v2) {
        cur[oc]      += v0 + v1 + v2;
        cur[16 + oc]  = fmaf(v0, v0, fmaf(v1, v1, fmaf(v2, v2, cur[16 + oc])));
    };

    auto accum4 = [&](const float4& A, const float4& Bq, const float4& Cq) {
        const float xs[4][3] = {{A.x,  A.y,  A.z },
                                {A.w,  Bq.x, Bq.y},
                                {Bq.z, Bq.w, Cq.x},
                                {Cq.y, Cq.z, Cq.w}};
#pragma unroll
        for (int g = 0; g < 8; ++g) {
            float4 w = sW1[gbase + g];           // 1 read / 4 samples
            float r[4][3];
#pragma unroll
            for (int m = 0; m < 4; ++m)
                conv3_relu(xs[m][0], xs[m][1], xs[m][2],
                           w.x, w.y, w.z, w.w, r[m][0], r[m][1], r[m][2]);
#pragma unroll
            for (int jj = 0; jj < 2; ++jj) {
                int oc = 2 * g + jj;             // 0..15, compile-time const
                int oo = 16 * p + oc;            // LDS address only
                float4 u = sU[oo];               // 1 read / 4 samples
                float2 cc = sC[oo];
#pragma unroll
                for (int m = 0; m < 4; ++m) {
                    float v0 = fmaxf(fmaf(u.y, r[m][0], fmaf(u.z, r[m][1], u.w)), 0.f);
                    float v1 = fmaxf(fmaf(u.x, r[m][0], fmaf(u.y, r[m][1], fmaf(u.z, r[m][2], cc.x))), 0.f);
                    float v2 = fmaxf(fmaf(u.x, r[m][1], fmaf(u.y, r[m][2], cc.y)), 0.f);
                    updc(oc, v0, v1, v2);
                }
            }
        }
    };

    auto accum1 = [&](float x0, float x1, float x2) {   // tail only
#pragma unroll
        for (int g = 0; g < 8; ++g) {
            float4 w = sW1[gbase + g];
            float r0, r1, r2;
            conv3_relu(x0, x1, x2, w.x, w.y, w.z, w.w, r0, r1, r2);
#pragma unroll
            for (int jj = 0; jj < 2; ++jj) {
                int oc = 2 * g + jj;
                int oo = 16 * p + oc;
                float4 u = sU[oo];
                float2 cc = sC[oo];
                float v0 = fmaxf(fmaf(u.y, r0, fmaf(u.z, r1, u.w)), 0.f);
                float v1 = fmaxf(fmaf(u.x, r0, fmaf(u.y, r1, fmaf(u.z, r2, cc.x))), 0.f);
                float v2 = fmaxf(fmaf(u.x, r1, fmaf(u.y, r2, cc.y)), 0.f);
                updc(oc, v0, v1, v2);
            }
        }
    };

    int nchunk = (B + 3) >> 2;
    int gp     = (blockIdx.x * 256 + t) >> 1;       // global pair id
    int stride = (gridDim.x * 256) >> 1;
    for (int ch = gp; ch < nchunk; ch += stride) {
        int s0 = ch << 2;
        if (s0 + 4 <= B) {
            const float4* xp = (const float4*)(x + (size_t)s0 * 3);
            float4 A = xp[0], Bq = xp[1], Cq = xp[2];
            accum4(A, Bq, Cq);
        } else {
            for (int m = 0; m < 4; ++m) {
                int s = s0 + m;
                if (s < B) accum1(x[3*s], x[3*s+1], x[3*s+2]);
            }
        }
    }

    // parity-preserving xor-tree: lane L ends with slot (L>>1) of its
    // parity's 32-slot vector.
    int lane = t & 63, wid = t >> 6;
#pragma unroll
    for (int half = 16; half >= 1; half >>= 1) {
        int d = half << 1;      // xor distance (keeps parity)
#pragma unroll
        for (int i = 0; i < half; ++i) {
            bool up = (lane & d);
            float keep = up ? cur[i + half] : cur[i];
            float send = up ? cur[i] : cur[i + half];
            cur[i] = keep + __shfl_xor(send, d, 64);
        }
    }
    __shared__ float red[4][64];
    {
        int idx = lane >> 1;
        int v = ((idx >> 4) << 5) + 16 * p + (idx & 15);
        red[wid][v] = cur[0];
    }
    __syncthreads();
    if (t < 64)
        atomicAdd(&accB[(blockIdx.x & (NSHARD_B - 1)) * 64 + t],
                  red[0][t] + red[1][t] + red[2][t] + red[3][t]);
}

// ---------------------------------------------------------------------------
// Pass 3: R11 main body with fixed-size shard prologue, __launch_bounds__
// (256,2) (R22-proven: fits at VGPR<=128, no spill). Byte-identical to R23.
// ---------------------------------------------------------------------------
__global__ __launch_bounds__(256, 2) void k_final(const float* __restrict__ x,
                                                  const float* __restrict__ w1,
                                                  const float* __restrict__ b1,
                                                  const float4* __restrict__ wU,
                                                  const float2* __restrict__ wC,
                                                  const float* __restrict__ accB,
                                                  const float* __restrict__ fw1,
                                                  const float* __restrict__ fb1,
                                                  const float* __restrict__ g2,
                                                  const float* __restrict__ bt2,
                                                  const float* __restrict__ fw2,
                                                  const float* __restrict__ fb2,
                                                  float* __restrict__ out,
                                                  float Ninv, int B)
{
    __shared__ float4 sW1[16];   // conv1 w + b
    __shared__ float4 sU[32];    // conv2 w + bias(pos0)
    __shared__ float2 sC[32];    // bias(pos1), bias(pos2)
    __shared__ float4 sFT[128];  // sFT[o*4+k] = fold(fw1)[o*16+4k .. +3]
    __shared__ float2 sJ[16];    // (c1[j], fw2[j])
    __shared__ float  sb2;
    __shared__ float  totB[64];
    __shared__ float  s2c[32], s2h[32];
    int t = threadIdx.x;
    if (t < 16) sW1[t] = make_float4(w1[3*t], w1[3*t+1], w1[3*t+2], b1[t]);
    else if (t >= 32 && t < 64) {
        int o = t - 32;
        sU[o] = wU[o];
        sC[o] = wC[o];
    } else if (t >= 64 && t < 128) {
        int v = t - 64;
        float s = 0.f;
#pragma unroll
        for (int sh = 0; sh < NSHARD_B; ++sh) s += accB[sh * 64 + v];
        totB[v] = s;
    } else if (t == 224) {
        sb2 = fb2[0];
    }
    __syncthreads();
    if (t < 32) {
        float mean = totB[t] * Ninv;
        float var  = fmaxf(totB[32 + t] * Ninv - mean * mean, 0.f);
        float sc = g2[t] * rsqrtf(var + EPSV);
        s2c[t] = sc;
        s2h[t] = bt2[t] - mean * sc;
    }
    __syncthreads();
    for (int idx = t; idx < 512; idx += 256) {
        int o = idx >> 4, j = idx & 15;
        ((float*)sFT)[o * 16 + j] = fw1[j * 32 + o] * s2c[o] * (1.0f / 3.0f);
    }
    if (t < 16) {
        float a = fb1[t];
#pragma unroll
        for (int c = 0; c < 32; ++c) a = fmaf(fw1[t * 32 + c], s2h[c], a);
        sJ[t] = make_float2(a, fw2[t]);
    }
    __syncthreads();

    int nchunk = (B + 3) >> 2;
    for (int ch = blockIdx.x * 256 + t; ch < nchunk; ch += gridDim.x * 256) {
        int s0 = ch << 2;
        if (s0 + 4 <= B) {
            const float4* xp = (const float4*)(x + (size_t)s0 * 3);
            float4 A = xp[0], Bq = xp[1], Cq = xp[2];
            const float xs[4][3] = {{A.x,  A.y,  A.z },
                                    {A.w,  Bq.x, Bq.y},
                                    {Bq.z, Bq.w, Cq.x},
                                    {Cq.y, Cq.z, Cq.w}};

            float acc[4][16];
#pragma unroll
            for (int m = 0; m < 4; ++m)
#pragma unroll
                for (int j = 0; j < 16; ++j) acc[m][j] = 0.f;

#pragma unroll 4
            for (int g = 0; g < 16; ++g) {
                float4 w = sW1[g];               // 1 read / 4 samples
                float r[4][3];
#pragma unroll
                for (int m = 0; m < 4; ++m)
                    conv3_relu(xs[m][0], xs[m][1], xs[m][2],
                               w.x, w.y, w.z, w.w, r[m][0], r[m][1], r[m][2]);
#pragma unroll
                for (int jj = 0; jj < 2; ++jj) {
                    int o = 2 * g + jj;
                    float4 u = sU[o];            // 1 read / 4 samples
                    float2 cc = sC[o];
                    float so[4];
#pragma unroll
                    for (int m = 0; m < 4; ++m) {
                        float v0 = fmaxf(fmaf(u.y, r[m][0], fmaf(u.z, r[m][1], u.w)), 0.f);
                        float v1 = fmaxf(fmaf(u.x, r[m][0], fmaf(u.y, r[m][1], fmaf(u.z, r[m][2], cc.x))), 0.f);
                        float v2 = fmaxf(fmaf(u.x, r[m][1], fmaf(u.y, r[m][2], cc.y)), 0.f);
                        so[m] = v0 + v1 + v2;
                    }
#pragma unroll
                    for (int k = 0; k < 4; ++k) {
                        float4 f = sFT[o * 4 + k];   // 1 read / 4 samples
#pragma unroll
                        for (int m = 0; m < 4; ++m) {
                            acc[m][4*k+0] = fmaf(f.x, so[m], acc[m][4*k+0]);
                            acc[m][4*k+1] = fmaf(f.y, so[m], acc[m][4*k+1]);
                            acc[m][4*k+2] = fmaf(f.z, so[m], acc[m][4*k+2]);
                            acc[m][4*k+3] = fmaf(f.w, so[m], acc[m][4*k+3]);
                        }
                    }
                }
            }

            float res[4];
#pragma unroll
            for (int m = 0; m < 4; ++m) res[m] = sb2;
#pragma unroll
            for (int j = 0; j < 16; ++j) {
                float2 jw = sJ[j];               // 1 read / 4 samples
#pragma unroll
                for (int m = 0; m < 4; ++m)
                    res[m] = fmaf(jw.y, fmaxf(acc[m][j] + jw.x, 0.f), res[m]);
            }
            *(float4*)(out + s0) = make_float4(res[0], res[1], res[2], res[3]);
        } else {
            // tail: per-sample path
            for (int m = 0; m < 4; ++m) {
                int s = s0 + m;
                if (s >= B) break;
                float x0 = x[3*s], x1 = x[3*s+1], x2 = x[3*s+2];
                float acc1[16];
#pragma unroll
                for (int j = 0; j < 16; ++j) acc1[j] = 0.f;
#pragma unroll 4
                for (int g = 0; g < 16; ++g) {
                    float4 w = sW1[g];
                    float r0, r1, r2;
                    conv3_relu(x0, x1, x2, w.x, w.y, w.z, w.w, r0, r1, r2);
#pragma unroll
                    for (int jj = 0; jj < 2; ++jj) {
                        int o = 2 * g + jj;
                        float4 u = sU[o];
                        float2 cc = sC[o];
                        float v0 = fmaxf(fmaf(u.y, r0, fmaf(u.z, r1, u.w)), 0.f);
                        float v1 = fmaxf(fmaf(u.x, r0, fmaf(u.y, r1, fmaf(u.z, r2, cc.x))), 0.f);
                        float v2 = fmaxf(fmaf(u.x, r1, fmaf(u.y, r2, cc.y)), 0.f);
                        float so = v0 + v1 + v2;
#pragma unroll
                        for (int k = 0; k < 4; ++k) {
                            float4 f = sFT[o * 4 + k];
                            acc1[4*k+0] = fmaf(f.x, so, acc1[4*k+0]);
                            acc1[4*k+1] = fmaf(f.y, so, acc1[4*k+1]);
                            acc1[4*k+2] = fmaf(f.z, so, acc1[4*k+2]);
                            acc1[4*k+3] = fmaf(f.w, so, acc1[4*k+3]);
                        }
                    }
                }
                float r = sb2;
#pragma unroll
                for (int j = 0; j < 16; ++j) {
                    float2 jw = sJ[j];
                    r = fmaf(jw.y, fmaxf(acc1[j] + jw.x, 0.f), r);
                }
                out[s] = r;
            }
        }
    }
}

// ---------------------------------------------------------------------------
extern "C" void kernel_launch(void* const* d_in, const int* in_sizes, int n_in,
                              void* d_out, int out_size, void* d_ws, size_t ws_size,
                              hipStream_t stream)
{
    const float* x   = (const float*)d_in[0];
    const float* w1  = (const float*)d_in[1];
    const float* b1  = (const float*)d_in[2];
    const float* g1  = (const float*)d_in[3];
    const float* bt1 = (const float*)d_in[4];
    const float* w2  = (const float*)d_in[5];
    const float* b2  = (const float*)d_in[6];
    const float* g2  = (const float*)d_in[7];
    const float* bt2 = (const float*)d_in[8];
    const float* fw1 = (const float*)d_in[9];
    const float* fb1 = (const float*)d_in[10];
    const float* fw2 = (const float*)d_in[11];
    const float* fb2 = (const float*)d_in[12];

    int B = in_sizes[0] / 3;

    // ws floats: p1 1024*32=32768 | accB 32*64=2048 | wU 128 | wC 64
    float*  ws   = (float*)d_ws;
    float*  p1   = ws;                          // 32768
    float*  accB = ws + 32768;                  // 2048
    float4* wU   = (float4*)(ws + 34816);       // 32 float4 (16B aligned)
    float2* wC   = (float2*)(ws + 34944);       // 32 float2

    float Ninv = 1.0f / (3.0f * (float)B);

    int nb1 = 1024;   // stats1: 1 chunk/thread (saturated)
    int nb2 = 2048;   // stats2: 1 chunk/pair (saturated)
    int nchunk = (B + 3) / 4;
    int gridF = (nchunk + 255) / 256;           // 4 samples/thread
    if (gridF > 2048) gridF = 2048;             // B=1M -> 1024 blocks

    // no memset: p1 fully overwritten; accB zeroed by k_stats1 blocks 0..7;
    // wU/wC fully overwritten by k_stats2 block 0.
    k_stats1<<<nb1, 256, 0, stream>>>(x, w1, b1, p1, accB, B);
    k_stats2<<<nb2, 256, 0, stream>>>(x, w1, b1, p1, g1, bt1, w2, b2,
                                      accB, wU, wC, Ninv, nb1, B);
    k_final<<<gridF, 256, 0, stream>>>(x, w1, b1, wU, wC, accB, fw1, fb1,
                                       g2, bt2, fw2, fb2, (float*)d_out,
                                       Ninv, B);
}

// Round 16
// 142.273 us; speedup vs baseline: 1.0822x; 1.0822x over previous
//
#include <hip/hip_runtime.h>
#include <math.h>

#define EPSV 1e-5f

// conv1 (3-tap, zero-pad) + relu at the 3 positions of one sample
__device__ __forceinline__ void conv3_relu(float x0, float x1, float x2,
                                           float wa, float wb, float wc, float bb,
                                           float& t0, float& t1, float& t2)
{
    t0 = fmaxf(fmaf(wb, x0, fmaf(wc, x1, bb)), 0.f);
    t1 = fmaxf(fmaf(wa, x0, fmaf(wb, x1, fmaf(wc, x2, bb))), 0.f);
    t2 = fmaxf(fmaf(wa, x1, fmaf(wb, x2, bb)), 0.f);
}

// ---------------------------------------------------------------------------
// R25 = R23 verbatim (142.3us session best), restoring after R24's regression
// (154.0us). R24 lesson completes the rule: nb-dependent reduction loops
// co-compiled into ANY kernel with a proven hot loop — prologue (R17: k_final
// 89.6 vs 40.6; R24: stats2 +10us) or epilogue (R18: stats2 65 vs <=40.6) —
// wreck its schedule. Fixed-size shard sums are the only safe in-kernel
// combine (R20: +3us). The memset node is cheap insurance.
// Structure: memset(2.5KB) + stats1(1024) + stats2(2048) + final(1024),
// sharded float atomicAdd combine (64 adds/addr), k_final = R11 body at
// __launch_bounds__(256,2) (VGPR<=128, no spill).
// ---------------------------------------------------------------------------

#define NSHARD_A 16   // stats1: nb1=1024 blocks -> 64 adds/addr
#define NSHARD_B 32   // stats2: nb2=2048 blocks -> 64 adds/addr

// ---------------------------------------------------------------------------
// Pass 1: per-channel sum/sumsq of relu(conv1(x)+b1), 16 ch.
// Group-outer / sample-inner. Tail: block-reduce in LDS then 32 sharded
// atomicAdds. accA[shard*32 + v]: v<16 sum, v>=16 sq.
// ---------------------------------------------------------------------------
__global__ __launch_bounds__(256) void k_stats1(const float* __restrict__ x,
                                                const float* __restrict__ w1,
                                                const float* __restrict__ b1,
                                                float* __restrict__ accA,
                                                int B)
{
    __shared__ float4 sW1[16];
    int t = threadIdx.x;
    if (t < 16) sW1[t] = make_float4(w1[3*t], w1[3*t+1], w1[3*t+2], b1[t]);
    __syncthreads();

    float cur[32];   // [0,16): sum, [16,32): sq
#pragma unroll
    for (int i = 0; i < 32; ++i) cur[i] = 0.f;

    auto upd = [&](int g, float t0, float t1, float t2) {
        cur[g]      += t0 + t1 + t2;
        cur[16 + g]  = fmaf(t0, t0, fmaf(t1, t1, fmaf(t2, t2, cur[16 + g])));
    };

    auto accum1 = [&](float x0, float x1, float x2) {   // tail only
#pragma unroll
        for (int g = 0; g < 16; ++g) {
            float4 w = sW1[g];
            float t0, t1, t2;
            conv3_relu(x0, x1, x2, w.x, w.y, w.z, w.w, t0, t1, t2);
            upd(g, t0, t1, t2);
        }
    };

    int nchunk = (B + 3) >> 2;
    for (int ch = blockIdx.x * 256 + t; ch < nchunk; ch += gridDim.x * 256) {
        int s0 = ch << 2;
        if (s0 + 4 <= B) {
            const float4* xp = (const float4*)(x + (size_t)s0 * 3);
            float4 A = xp[0], Bq = xp[1], Cq = xp[2];
            const float xs[4][3] = {{A.x,  A.y,  A.z },
                                    {A.w,  Bq.x, Bq.y},
                                    {Bq.z, Bq.w, Cq.x},
                                    {Cq.y, Cq.z, Cq.w}};
#pragma unroll
            for (int g = 0; g < 16; ++g) {
                float4 w = sW1[g];           // 1 LDS read per 4 samples
#pragma unroll
                for (int m = 0; m < 4; ++m) {
                    float t0, t1, t2;
                    conv3_relu(xs[m][0], xs[m][1], xs[m][2],
                               w.x, w.y, w.z, w.w, t0, t1, t2);
                    upd(g, t0, t1, t2);
                }
            }
        } else {
            for (int m = 0; m < 4; ++m) {
                int s = s0 + m;
                if (s < B) accum1(x[3*s], x[3*s+1], x[3*s+2]);
            }
        }
    }

    // xor-tree: lane (L&31) ends holding total of slot (L&31)  [R3-proven]
    int lane = t & 63, wid = t >> 6;
#pragma unroll
    for (int i = 0; i < 32; ++i) cur[i] += __shfl_xor(cur[i], 32, 64);
#pragma unroll
    for (int half = 16; half >= 1; half >>= 1) {
#pragma unroll
        for (int i = 0; i < half; ++i) {
            bool up = (lane & half);
            float keep = up ? cur[i + half] : cur[i];
            float send = up ? cur[i] : cur[i + half];
            cur[i] = keep + __shfl_xor(send, half, 64);
        }
    }
    __shared__ float red[4][32];
    if (lane < 32) red[wid][lane] = cur[0];
    __syncthreads();
    if (t < 32)
        atomicAdd(&accA[(blockIdx.x & (NSHARD_A - 1)) * 32 + t],
                  red[0][t] + red[1][t] + red[2][t] + red[3][t]);
}

// ---------------------------------------------------------------------------
// Pass 2: conv2 per-channel stats, lane-pair split (parity p=tid&1 owns conv
// groups [8p,8p+8)). Prologue: sum 16 shards -> BN1 -> sU/sC (fixed-size).
// Block 0 publishes sU/sC to global wU/wC for k_final. Tail: 64 sharded
// atomicAdds into 32 shards. NO epilogue (R18 poison), NO loop prologue
// (R24 poison).
// accB[shard*64 + v]: v<32 sum ch v, v>=32 sq ch v-32.
// ---------------------------------------------------------------------------
__global__ __launch_bounds__(256) void k_stats2(const float* __restrict__ x,
                                                const float* __restrict__ w1,
                                                const float* __restrict__ b1,
                                                const float* __restrict__ accA,
                                                const float* __restrict__ g1,
                                                const float* __restrict__ bt1,
                                                const float* __restrict__ w2,
                                                const float* __restrict__ b2,
                                                float* __restrict__ accB,
                                                float4* __restrict__ wU,
                                                float2* __restrict__ wC,
                                                float Ninv, int B)
{
    __shared__ float4 sW1[16];
    __shared__ float4 sU[32];   // ua,ub,uc,c0
    __shared__ float2 sC[32];   // c1,c2
    __shared__ float tot[32];
    __shared__ float ssc[16], ssh[16];
    int t = threadIdx.x;

    // ---- BN1 consts from sharded totals (fixed-size prologue)
    if (t < 16) sW1[t] = make_float4(w1[3*t], w1[3*t+1], w1[3*t+2], b1[t]);
    else if (t >= 32 && t < 64) {
        int v = t - 32;
        float s = 0.f;
#pragma unroll
        for (int sh = 0; sh < NSHARD_A; ++sh) s += accA[sh * 32 + v];
        tot[v] = s;
    }
    __syncthreads();
    if (t < 16) {
        float mean = tot[t] * Ninv;
        float var  = fmaxf(tot[16 + t] * Ninv - mean * mean, 0.f);
        float rstd = rsqrtf(var + EPSV);
        float sc = g1[t] * rstd;
        ssc[t] = sc;
        ssh[t] = bt1[t] - mean * sc;
    }
    __syncthreads();
    if (t < 32) {
        int o = t, g = o >> 1;
        float sc = ssc[g], sh = ssh[g];
        float wv0 = w2[3*o], wv1 = w2[3*o+1], wv2 = w2[3*o+2];
        sU[o] = make_float4(wv0 * sc, wv1 * sc, wv2 * sc,
                            b2[o] + sh * (wv1 + wv2));          // bias pos0
        sC[o] = make_float2(b2[o] + sh * (wv0 + wv1 + wv2),     // bias pos1
                            b2[o] + sh * (wv0 + wv1));          // bias pos2
    }
    __syncthreads();
    // block 0 publishes folded conv2 tables for k_final (kernel boundary
    // orders these stores vs k_final's loads)
    if (blockIdx.x == 0 && t < 32) { wU[t] = sU[t]; wC[t] = sC[t]; }

    const int p = t & 1;        // parity: which half of the channels
    const int gbase = 8 * p;    // conv groups [gbase, gbase+8)

    float cur[32];  // [0,16): sum ch 16p+i, [16,32): sq ch 16p+i
#pragma unroll
    for (int i = 0; i < 32; ++i) cur[i] = 0.f;

    auto updc = [&](int oc, float v0, float v1, float v2) {
        cur[oc]      += v0 + v1 + v2;
        cur[16 + oc]  = fmaf(v0, v0, fmaf(v1, v1, fmaf(v2, v2, cur[16 + oc])));
    };

    auto accum4 = [&](const float4& A, const float4& Bq, const float4& Cq) {
        const float xs[4][3] = {{A.x,  A.y,  A.z },
                                {A.w,  Bq.x, Bq.y},
                                {Bq.z, Bq.w, Cq.x},
                                {Cq.y, Cq.z, Cq.w}};
#pragma unroll
        for (int g = 0; g < 8; ++g) {
            float4 w = sW1[gbase + g];           // 1 read / 4 samples
            float r[4][3];
#pragma unroll
            for (int m = 0; m < 4; ++m)
                conv3_relu(xs[m][0], xs[m][1], xs[m][2],
                           w.x, w.y, w.z, w.w, r[m][0], r[m][1], r[m][2]);
#pragma unroll
            for (int jj = 0; jj < 2; ++jj) {
                int oc = 2 * g + jj;             // 0..15, compile-time const
                int oo = 16 * p + oc;            // LDS address only
                float4 u = sU[oo];               // 1 read / 4 samples
                float2 cc = sC[oo];
#pragma unroll
                for (int m = 0; m < 4; ++m) {
                    float v0 = fmaxf(fmaf(u.y, r[m][0], fmaf(u.z, r[m][1], u.w)), 0.f);
                    float v1 = fmaxf(fmaf(u.x, r[m][0], fmaf(u.y, r[m][1], fmaf(u.z, r[m][2], cc.x))), 0.f);
                    float v2 = fmaxf(fmaf(u.x, r[m][1], fmaf(u.y, r[m][2], cc.y)), 0.f);
                    updc(oc, v0, v1, v2);
                }
            }
        }
    };

    auto accum1 = [&](float x0, float x1, float x2) {   // tail only
#pragma unroll
        for (int g = 0; g < 8; ++g) {
            float4 w = sW1[gbase + g];
            float r0, r1, r2;
            conv3_relu(x0, x1, x2, w.x, w.y, w.z, w.w, r0, r1, r2);
#pragma unroll
            for (int jj = 0; jj < 2; ++jj) {
                int oc = 2 * g + jj;
                int oo = 16 * p + oc;
                float4 u = sU[oo];
                float2 cc = sC[oo];
                float v0 = fmaxf(fmaf(u.y, r0, fmaf(u.z, r1, u.w)), 0.f);
                float v1 = fmaxf(fmaf(u.x, r0, fmaf(u.y, r1, fmaf(u.z, r2, cc.x))), 0.f);
                float v2 = fmaxf(fmaf(u.x, r1, fmaf(u.y, r2, cc.y)), 0.f);
                updc(oc, v0, v1, v2);
            }
        }
    };

    int nchunk = (B + 3) >> 2;
    int gp     = (blockIdx.x * 256 + t) >> 1;       // global pair id
    int stride = (gridDim.x * 256) >> 1;
    for (int ch = gp; ch < nchunk; ch += stride) {
        int s0 = ch << 2;
        if (s0 + 4 <= B) {
            const float4* xp = (const float4*)(x + (size_t)s0 * 3);
            float4 A = xp[0], Bq = xp[1], Cq = xp[2];
            accum4(A, Bq, Cq);
        } else {
            for (int m = 0; m < 4; ++m) {
                int s = s0 + m;
                if (s < B) accum1(x[3*s], x[3*s+1], x[3*s+2]);
            }
        }
    }

    // parity-preserving xor-tree: lane L ends with slot (L>>1) of its
    // parity's 32-slot vector.
    int lane = t & 63, wid = t >> 6;
#pragma unroll
    for (int half = 16; half >= 1; half >>= 1) {
        int d = half << 1;      // xor distance (keeps parity)
#pragma unroll
        for (int i = 0; i < half; ++i) {
            bool up = (lane & d);
            float keep = up ? cur[i + half] : cur[i];
            float send = up ? cur[i] : cur[i + half];
            cur[i] = keep + __shfl_xor(send, d, 64);
        }
    }
    __shared__ float red[4][64];
    {
        int idx = lane >> 1;
        int v = ((idx >> 4) << 5) + 16 * p + (idx & 15);
        red[wid][v] = cur[0];
    }
    __syncthreads();
    if (t < 64)
        atomicAdd(&accB[(blockIdx.x & (NSHARD_B - 1)) * 64 + t],
                  red[0][t] + red[1][t] + red[2][t] + red[3][t]);
}

// ---------------------------------------------------------------------------
// Pass 3: R11 main body with fixed-size shard prologue, __launch_bounds__
// (256,2) (R22-proven: fits at VGPR<=128, no spill, <43us).
// ---------------------------------------------------------------------------
__global__ __launch_bounds__(256, 2) void k_final(const float* __restrict__ x,
                                                  const float* __restrict__ w1,
                                                  const float* __restrict__ b1,
                                                  const float4* __restrict__ wU,
                                                  const float2* __restrict__ wC,
                                                  const float* __restrict__ accB,
                                                  const float* __restrict__ fw1,
                                                  const float* __restrict__ fb1,
                                                  const float* __restrict__ g2,
                                                  const float* __restrict__ bt2,
                                                  const float* __restrict__ fw2,
                                                  const float* __restrict__ fb2,
                                                  float* __restrict__ out,
                                                  float Ninv, int B)
{
    __shared__ float4 sW1[16];   // conv1 w + b
    __shared__ float4 sU[32];    // conv2 w + bias(pos0)
    __shared__ float2 sC[32];    // bias(pos1), bias(pos2)
    __shared__ float4 sFT[128];  // sFT[o*4+k] = fold(fw1)[o*16+4k .. +3]
    __shared__ float2 sJ[16];    // (c1[j], fw2[j])
    __shared__ float  sb2;
    __shared__ float  totB[64];
    __shared__ float  s2c[32], s2h[32];
    int t = threadIdx.x;
    if (t < 16) sW1[t] = make_float4(w1[3*t], w1[3*t+1], w1[3*t+2], b1[t]);
    else if (t >= 32 && t < 64) {
        int o = t - 32;
        sU[o] = wU[o];
        sC[o] = wC[o];
    } else if (t >= 64 && t < 128) {
        int v = t - 64;
        float s = 0.f;
#pragma unroll
        for (int sh = 0; sh < NSHARD_B; ++sh) s += accB[sh * 64 + v];
        totB[v] = s;
    } else if (t == 224) {
        sb2 = fb2[0];
    }
    __syncthreads();
    if (t < 32) {
        float mean = totB[t] * Ninv;
        float var  = fmaxf(totB[32 + t] * Ninv - mean * mean, 0.f);
        float sc = g2[t] * rsqrtf(var + EPSV);
        s2c[t] = sc;
        s2h[t] = bt2[t] - mean * sc;
    }
    __syncthreads();
    for (int idx = t; idx < 512; idx += 256) {
        int o = idx >> 4, j = idx & 15;
        ((float*)sFT)[o * 16 + j] = fw1[j * 32 + o] * s2c[o] * (1.0f / 3.0f);
    }
    if (t < 16) {
        float a = fb1[t];
#pragma unroll
        for (int c = 0; c < 32; ++c) a = fmaf(fw1[t * 32 + c], s2h[c], a);
        sJ[t] = make_float2(a, fw2[t]);
    }
    __syncthreads();

    int nchunk = (B + 3) >> 2;
    for (int ch = blockIdx.x * 256 + t; ch < nchunk; ch += gridDim.x * 256) {
        int s0 = ch << 2;
        if (s0 + 4 <= B) {
            const float4* xp = (const float4*)(x + (size_t)s0 * 3);
            float4 A = xp[0], Bq = xp[1], Cq = xp[2];
            const float xs[4][3] = {{A.x,  A.y,  A.z },
                                    {A.w,  Bq.x, Bq.y},
                                    {Bq.z, Bq.w, Cq.x},
                                    {Cq.y, Cq.z, Cq.w}};

            float acc[4][16];
#pragma unroll
            for (int m = 0; m < 4; ++m)
#pragma unroll
                for (int j = 0; j < 16; ++j) acc[m][j] = 0.f;

#pragma unroll 4
            for (int g = 0; g < 16; ++g) {
                float4 w = sW1[g];               // 1 read / 4 samples
                float r[4][3];
#pragma unroll
                for (int m = 0; m < 4; ++m)
                    conv3_relu(xs[m][0], xs[m][1], xs[m][2],
                               w.x, w.y, w.z, w.w, r[m][0], r[m][1], r[m][2]);
#pragma unroll
                for (int jj = 0; jj < 2; ++jj) {
                    int o = 2 * g + jj;
                    float4 u = sU[o];            // 1 read / 4 samples
                    float2 cc = sC[o];
                    float so[4];
#pragma unroll
                    for (int m = 0; m < 4; ++m) {
                        float v0 = fmaxf(fmaf(u.y, r[m][0], fmaf(u.z, r[m][1], u.w)), 0.f);
                        float v1 = fmaxf(fmaf(u.x, r[m][0], fmaf(u.y, r[m][1], fmaf(u.z, r[m][2], cc.x))), 0.f);
                        float v2 = fmaxf(fmaf(u.x, r[m][1], fmaf(u.y, r[m][2], cc.y)), 0.f);
                        so[m] = v0 + v1 + v2;
                    }
#pragma unroll
                    for (int k = 0; k < 4; ++k) {
                        float4 f = sFT[o * 4 + k];   // 1 read / 4 samples
#pragma unroll
                        for (int m = 0; m < 4; ++m) {
                            acc[m][4*k+0] = fmaf(f.x, so[m], acc[m][4*k+0]);
                            acc[m][4*k+1] = fmaf(f.y, so[m], acc[m][4*k+1]);
                            acc[m][4*k+2] = fmaf(f.z, so[m], acc[m][4*k+2]);
                            acc[m][4*k+3] = fmaf(f.w, so[m], acc[m][4*k+3]);
                        }
                    }
                }
            }

            float res[4];
#pragma unroll
            for (int m = 0; m < 4; ++m) res[m] = sb2;
#pragma unroll
            for (int j = 0; j < 16; ++j) {
                float2 jw = sJ[j];               // 1 read / 4 samples
#pragma unroll
                for (int m = 0; m < 4; ++m)
                    res[m] = fmaf(jw.y, fmaxf(acc[m][j] + jw.x, 0.f), res[m]);
            }
            *(float4*)(out + s0) = make_float4(res[0], res[1], res[2], res[3]);
        } else {
            // tail: per-sample path
            for (int m = 0; m < 4; ++m) {
                int s = s0 + m;
                if (s >= B) break;
                float x0 = x[3*s], x1 = x[3*s+1], x2 = x[3*s+2];
                float acc1[16];
#pragma unroll
                for (int j = 0; j < 16; ++j) acc1[j] = 0.f;
#pragma unroll 4
                for (int g = 0; g < 16; ++g) {
                    float4 w = sW1[g];
                    float r0, r1, r2;
                    conv3_relu(x0, x1, x2, w.x, w.y, w.z, w.w, r0, r1, r2);
#pragma unroll
                    for (int jj = 0; jj < 2; ++jj) {
                        int o = 2 * g + jj;
                        float4 u = sU[o];
                        float2 cc = sC[o];
                        float v0 = fmaxf(fmaf(u.y, r0, fmaf(u.z, r1, u.w)), 0.f);
                        float v1 = fmaxf(fmaf(u.x, r0, fmaf(u.y, r1, fmaf(u.z, r2, cc.x))), 0.f);
                        float v2 = fmaxf(fmaf(u.x, r1, fmaf(u.y, r2, cc.y)), 0.f);
                        float so = v0 + v1 + v2;
#pragma unroll
                        for (int k = 0; k < 4; ++k) {
                            float4 f = sFT[o * 4 + k];
                            acc1[4*k+0] = fmaf(f.x, so, acc1[4*k+0]);
                            acc1[4*k+1] = fmaf(f.y, so, acc1[4*k+1]);
                            acc1[4*k+2] = fmaf(f.z, so, acc1[4*k+2]);
                            acc1[4*k+3] = fmaf(f.w, so, acc1[4*k+3]);
                        }
                    }
                }
                float r = sb2;
#pragma unroll
                for (int j = 0; j < 16; ++j) {
                    float2 jw = sJ[j];
                    r = fmaf(jw.y, fmaxf(acc1[j] + jw.x, 0.f), r);
                }
                out[s] = r;
            }
        }
    }
}

// ---------------------------------------------------------------------------
extern "C" void kernel_launch(void* const* d_in, const int* in_sizes, int n_in,
                              void* d_out, int out_size, void* d_ws, size_t ws_size,
                              hipStream_t stream)
{
    const float* x   = (const float*)d_in[0];
    const float* w1  = (const float*)d_in[1];
    const float* b1  = (const float*)d_in[2];
    const float* g1  = (const float*)d_in[3];
    const float* bt1 = (const float*)d_in[4];
    const float* w2  = (const float*)d_in[5];
    const float* b2  = (const float*)d_in[6];
    const float* g2  = (const float*)d_in[7];
    const float* bt2 = (const float*)d_in[8];
    const float* fw1 = (const float*)d_in[9];
    const float* fb1 = (const float*)d_in[10];
    const float* fw2 = (const float*)d_in[11];
    const float* fb2 = (const float*)d_in[12];

    int B = in_sizes[0] / 3;

    // ws floats: accA 16*32=512 | accB 32*64=2048 | wU 128 | wC 64 (=2752)
    float*  ws   = (float*)d_ws;
    float*  accA = ws;                          // 512
    float*  accB = ws + 512;                    // 2048
    float4* wU   = (float4*)(ws + 2560);        // 32 float4 (16B aligned)
    float2* wC   = (float2*)(ws + 2688);        // 32 float2

    float Ninv = 1.0f / (3.0f * (float)B);

    int nb1 = 1024;   // stats1: 1 chunk/thread (saturated)
    int nb2 = 2048;   // stats2: 1 chunk/pair (saturated)
    int nchunk = (B + 3) / 4;
    int gridF = (nchunk + 255) / 256;           // 4 samples/thread
    if (gridF > 2048) gridF = 2048;             // B=1M -> 1024 blocks

    // zero the sharded accumulators (ws is poison-filled each iteration)
    hipMemsetAsync(ws, 0, 2560 * sizeof(float), stream);

    k_stats1<<<nb1, 256, 0, stream>>>(x, w1, b1, accA, B);
    k_stats2<<<nb2, 256, 0, stream>>>(x, w1, b1, accA, g1, bt1, w2, b2,
                                      accB, wU, wC, Ninv, B);
    k_final<<<gridF, 256, 0, stream>>>(x, w1, b1, wU, wC, accB, fw1, fb1,
                                       g2, bt2, fw2, fb2, (float*)d_out,
                                       Ninv, B);
}